// Round 9
// baseline (448.820 us; speedup 1.0000x reference)
//
#include <hip/hip_runtime.h>

// Spiking self-attention (Spikformer SSA) forward — 128x128 MFMA GEMMs with
// BN stats fused into the epilogue (fp64 partials, deterministic fold).
// qkv: 3-way bf16 split weights (flip-safe); proj: 2-way split (no downstream
// thresholding). proj writes into d_out, BN2 in-place. T=16,B=8,N=196,C=512.

#define TT 16
#define BB 8
#define NNQ 196
#define CC 512
#define HH 8
#define HD 64
#define O3 1536
#define BN (BB*NNQ)          // 1568
#define PT (BN*CC)           // 802816
#define WTOT ((O3+CC)*CC)    // 1048576 split-weight elems

static constexpr float VTH = 0.5f;
typedef __attribute__((ext_vector_type(8))) short short8;
typedef __attribute__((ext_vector_type(4))) float f32x4;
typedef unsigned short u16;

__device__ __forceinline__ float sigm(float w){ return 1.f/(1.f+expf(-w)); }

__device__ __forceinline__ float lif_step(float x, float& v, float sg){
  float d  = __fsub_rn(x, v);
  float dd = __fmul_rn(d, sg);
  v = __fadd_rn(v, dd);
  float sp = (v >= VTH) ? 1.f : 0.f;
  v = __fmul_rn(v, __fsub_rn(1.f, sp));
  return sp;
}

__device__ __forceinline__ u16 bf16_rn(float x){
  unsigned u = __float_as_uint(x);
  unsigned r = u + 0x7FFF + ((u>>16)&1);
  return (u16)(r>>16);
}
__device__ __forceinline__ float bf16_to_f(u16 h){
  return __uint_as_float(((unsigned)h)<<16);
}

__device__ __forceinline__ void gld_lds16(const void* g, void* l){
  __builtin_amdgcn_global_load_lds(
    (const __attribute__((address_space(1))) unsigned int*)g,
    (__attribute__((address_space(3))) unsigned int*)l, 16, 0, 0);
}

// ---- split weights into hi/mid/lo bf16 ----
__global__ void k_wsplit(const float* __restrict__ qkv_w, const float* __restrict__ proj_w,
                         u16* __restrict__ whi, u16* __restrict__ wmid, u16* __restrict__ wlo){
  int i = blockIdx.x*256 + threadIdx.x;
  float w = (i < O3*CC) ? qkv_w[i] : proj_w[i - O3*CC];
  u16 h = bf16_rn(w);          float r1 = w - bf16_to_f(h);
  u16 m = bf16_rn(r1);         float r2 = r1 - bf16_to_f(m);
  u16 l = bf16_rn(r2);
  whi[i]=h; wmid[i]=m; wlo[i]=l;
}

// ---- LIF scan on input x -> bf16 spikes ----
__global__ void k_lif_x(const float* __restrict__ x, const float* __restrict__ w,
                        float* __restrict__ vin, u16* __restrict__ s0, int t0, int tc){
  int g = blockIdx.x*256 + threadIdx.x;
  float sg = sigm(w[0]);
  float v = (t0==0) ? 0.f : vin[g];
  for (int tt=0; tt<tc; ++tt){
    float sp = lif_step(x[(size_t)(t0+tt)*PT + g], v, sg);
    s0[(size_t)tt*PT + g] = (sp!=0.f) ? 0x3F80 : 0;
  }
  vin[g] = v;
}

// ---- C[M,ON] = A(bf16 0/1)*(sum of NS split weights)^T + bias,
//      fused per-block fp64 BN partial stats. 128x128 tile. ----
template<int ON, int NS>
__global__ __launch_bounds__(256, 2)
void k_gemm_mfma(const u16* __restrict__ A, const u16* __restrict__ Wh,
                 const u16* __restrict__ Wm, const u16* __restrict__ Wl,
                 const float* __restrict__ bias, float* __restrict__ Cm,
                 double* __restrict__ psum, double* __restrict__ psq, int M){
  __shared__ __align__(16) u16 Al[128][64];
  __shared__ __align__(16) u16 Bs[NS][128][64];
  const u16* __restrict__ Ws[3] = {Wh, Wm, Wl};
  const int nON = ON/128;
  int nwg = gridDim.x;
  int bid = blockIdx.x;
  int q = nwg >> 3, r = nwg & 7;
  int xcd = bid & 7, idx = bid >> 3;
  int wgid = (xcd < r ? xcd*(q+1) : r*(q+1) + (xcd-r)*q) + idx;
  int mb = wgid / nON, ob = wgid - mb*nON;
  int m0 = mb*128, o0 = ob*128;

  int tid = threadIdx.x;
  int w = tid>>6, lane = tid&63;
  int wm = (w&1)*64, wn = (w>>1)*64;
  int r16 = lane&15, kg = lane>>4;
  int lrow = w*32 + (lane>>3);
  int lslot = lane&7;
  f32x4 acc[4][4] = {};
  for (int k0=0;k0<512;k0+=64){
    #pragma unroll
    for (int i=0;i<4;++i){
      int row = lrow + i*8;
      int gslot = lslot ^ (row&7);
      int gr = m0+row; if (gr>=M) gr=M-1;
      gld_lds16(&A[(size_t)gr*512 + k0 + gslot*8], &Al[w*32+i*8][0]);
      #pragma unroll
      for (int sp=0; sp<NS; ++sp)
        gld_lds16(&Ws[sp][(size_t)(o0+row)*512 + k0 + gslot*8], &Bs[sp][w*32+i*8][0]);
    }
    __syncthreads();
    #pragma unroll
    for (int s=0;s<2;++s){
      short8 af[4], bfr[NS][4];
      #pragma unroll
      for (int mt=0;mt<4;++mt){
        int rr = wm + mt*16 + r16;
        af[mt] = *(const short8*)&Al[rr][((s*4+kg)^(rr&7))*8];
      }
      #pragma unroll
      for (int nt=0;nt<4;++nt){
        int rr = wn + nt*16 + r16;
        int sl = ((s*4+kg)^(rr&7))*8;
        #pragma unroll
        for (int sp=0; sp<NS; ++sp)
          bfr[sp][nt] = *(const short8*)&Bs[sp][rr][sl];
      }
      #pragma unroll
      for (int mt=0;mt<4;++mt)
        #pragma unroll
        for (int nt=0;nt<4;++nt)
          #pragma unroll
          for (int sp=0; sp<NS; ++sp)
            acc[mt][nt] = __builtin_amdgcn_mfma_f32_16x16x32_bf16(af[mt], bfr[sp][nt], acc[mt][nt],0,0,0);
    }
    __syncthreads();
  }
  // epilogue: C-write + fp64 column partial stats (value == stored value)
  int bseg = (m0/1568 + 1)*1568;
  double ssm[4][2] = {}, ssq2[4][2] = {};
  #pragma unroll
  for (int nt=0; nt<4; ++nt){
    int o = o0 + wn + nt*16 + r16;
    float bs = bias[o];
    #pragma unroll
    for (int mt=0; mt<4; ++mt){
      #pragma unroll
      for (int i=0;i<4;++i){
        int m = m0 + wm + mt*16 + kg*4 + i;
        if (m < M){
          float val = acc[mt][nt][i] + bs;
          Cm[(size_t)m*ON + o] = val;
          int sg = (m >= bseg) ? 1 : 0;
          ssm[nt][sg]  += (double)val;
          ssq2[nt][sg] += (double)val*(double)val;
        }
      }
    }
  }
  #pragma unroll
  for (int nt=0;nt<4;++nt)
    #pragma unroll
    for (int sg=0;sg<2;++sg){
      ssm[nt][sg]  += __shfl_xor(ssm[nt][sg], 16);
      ssm[nt][sg]  += __shfl_xor(ssm[nt][sg], 32);
      ssq2[nt][sg] += __shfl_xor(ssq2[nt][sg], 16);
      ssq2[nt][sg] += __shfl_xor(ssq2[nt][sg], 32);
    }
  double* statd = (double*)&Al[0][0];   // 8KB reuse; all waves past final barrier
  if (lane < 16){
    #pragma unroll
    for (int nt=0;nt<4;++nt)
      #pragma unroll
      for (int sg=0;sg<2;++sg){
        int bi = (((w*4+nt)*16 + r16)*2 + sg)*2;
        statd[bi+0] = ssm[nt][sg];
        statd[bi+1] = ssq2[nt][sg];
      }
  }
  __syncthreads();
  {
    int sg = tid & 1, ol = tid >> 1;          // ol = 0..127
    int nh = ol>>6, ntv = (ol&63)>>4, rv = ol&15;
    int i0 = ((((2*nh+0)*4+ntv)*16 + rv)*2 + sg)*2;
    int i1 = ((((2*nh+1)*4+ntv)*16 + rv)*2 + sg)*2;
    size_t pi = ((size_t)mb*2 + sg)*ON + o0 + ol;
    psum[pi] = statd[i0+0] + statd[i1+0];
    psq [pi] = statd[i0+1] + statd[i1+1];
  }
}

// ---- fold per-block partials -> mean/rstd (deterministic, fp64) ----
template<int O>
__global__ void k_stat_fold(const double* __restrict__ psum, const double* __restrict__ psq,
                            float* __restrict__ mean, float* __restrict__ rstd,
                            int nmb, int total){
  int i = blockIdx.x*256 + threadIdx.x;
  if (i >= total) return;
  int tt = i / O, o = i - tt*O;
  double s=0.0, qq=0.0;
  for (int mb=0; mb<nmb; ++mb){
    int tb = (mb*128)/1568;
    int sg = tt - tb;
    if (sg==0 || sg==1){
      size_t pi = ((size_t)mb*2 + sg)*O + o;
      s += psum[pi]; qq += psq[pi];
    }
  }
  double m = s*(1.0/BN);
  double var = qq*(1.0/BN) - m*m;
  mean[i] = (float)m;
  rstd[i] = (float)(1.0/sqrt(var+1e-5));
}

// ---- BN1 + LIF scan q/k/v -> bf16 spikes [tt,b,h,n,d] ----
__global__ void k_lif_qkv(const float* __restrict__ qkv, const float* __restrict__ mean,
                          const float* __restrict__ rstd, const float* __restrict__ g1,
                          const float* __restrict__ b1,
                          const float* __restrict__ wq, const float* __restrict__ wk,
                          const float* __restrict__ wv,
                          float* __restrict__ vq, float* __restrict__ vk, float* __restrict__ vv,
                          u16* __restrict__ qs, u16* __restrict__ ks,
                          u16* __restrict__ vs, int t0, int tc){
  int g = blockIdx.x*256 + threadIdx.x;
  int j = blockIdx.y;
  int d = g & 63;
  int n = (g>>6) % NNQ;
  int h = (g/(NNQ*64)) & 7;
  int b = g/(NNQ*64*8);
  int o = j*CC + h*HD + d;
  const float* w = (j==0)? wq : (j==1)? wk : wv;
  float* st  = (j==0)? vq : (j==1)? vk : vv;
  u16* out = (j==0)? qs : (j==1)? ks : vs;
  float sg = sigm(w[0]);
  float v = (t0==0) ? 0.f : st[g];
  size_t row = (size_t)(b*NNQ + n)*O3 + o;
  for (int tt=0; tt<tc; ++tt){
    float xv = qkv[(size_t)tt*BN*O3 + row];
    int so = tt*O3 + o;
    int go = (t0+tt)*O3 + o;
    float xn = __fadd_rn(__fmul_rn(__fmul_rn(__fsub_rn(xv, mean[so]), rstd[so]),
                                   g1[go]), b1[go]);
    float sp = lif_step(xn, v, sg);
    out[(size_t)tt*PT + g] = (sp!=0.f) ? 0x3F80 : 0;
  }
  st[g] = v;
}

// ---- per (tt,b,h): kv = K^T V (MFMA), then attn = 0.125 * Q kv (MFMA) ----
__global__ __launch_bounds__(256)
void k_kvqv_mfma(const u16* __restrict__ ks, const u16* __restrict__ vs,
                 const u16* __restrict__ qs, float* __restrict__ attn){
  __shared__ __align__(16) u16 Kb[224][64];
  __shared__ __align__(16) u16 Vb[224][64];
  __shared__ __align__(16) u16 kvb[64][64];
  int blk = blockIdx.x;
  size_t base = (size_t)blk * (NNQ*HD);
  int tid = threadIdx.x, w = tid>>6, lane = tid&63;
  int r16 = lane&15, kg = lane>>4;
  for (int u=tid; u<224*8; u+=256){
    int row=u>>3, slot=u&7;
    float4 z = {0.f,0.f,0.f,0.f};
    float4 kd = z, vd = z;
    if (row < NNQ){
      kd = *(const float4*)&ks[base + (size_t)row*64 + slot*8];
      vd = *(const float4*)&vs[base + (size_t)row*64 + slot*8];
    }
    *(float4*)&Kb[row][slot*8] = kd;
    *(float4*)&Vb[row][slot*8] = vd;
  }
  __syncthreads();
  f32x4 acc[4] = {};
  int d0 = w*16;
  for (int n0=0;n0<224;n0+=32){
    short8 af;
    #pragma unroll
    for (int jj=0;jj<8;++jj) af[jj] = (short)Kb[n0+kg*8+jj][d0 + r16];
    #pragma unroll
    for (int nt=0;nt<4;++nt){
      short8 bf;
      #pragma unroll
      for (int jj=0;jj<8;++jj) bf[jj] = (short)Vb[n0+kg*8+jj][nt*16 + r16];
      acc[nt] = __builtin_amdgcn_mfma_f32_16x16x32_bf16(af, bf, acc[nt],0,0,0);
    }
  }
  #pragma unroll
  for (int nt=0;nt<4;++nt)
    #pragma unroll
    for (int i=0;i<4;++i)
      kvb[d0 + kg*4 + i][nt*16 + r16] = (u16)(__float_as_uint(acc[nt][i])>>16);
  __syncthreads();
  for (int u=tid; u<224*8; u+=256){
    int row=u>>3, slot=u&7;
    int sl = slot ^ (row&7);
    float4 qd = {0.f,0.f,0.f,0.f};
    if (row < NNQ) qd = *(const float4*)&qs[base + (size_t)row*64 + slot*8];
    *(float4*)&Kb[row][sl*8] = qd;
  }
  __syncthreads();
  short8 bkv[2][4];
  #pragma unroll
  for (int s=0;s<2;++s)
    #pragma unroll
    for (int nt=0;nt<4;++nt){
      short8 bf;
      #pragma unroll
      for (int jj=0;jj<8;++jj) bf[jj] = (short)kvb[s*32 + kg*8 + jj][nt*16 + r16];
      bkv[s][nt] = bf;
    }
  for (int mt=w; mt<13; mt+=4){
    f32x4 a2[4] = {};
    short8 qa[2];
    #pragma unroll
    for (int s=0;s<2;++s){
      int rr = mt*16 + r16;
      qa[s] = *(const short8*)&Kb[rr][(((s*4+kg)^(rr&7)))*8];
    }
    #pragma unroll
    for (int s=0;s<2;++s)
      #pragma unroll
      for (int nt=0;nt<4;++nt)
        a2[nt] = __builtin_amdgcn_mfma_f32_16x16x32_bf16(qa[s], bkv[s][nt], a2[nt],0,0,0);
    #pragma unroll
    for (int nt=0;nt<4;++nt){
      int e = nt*16 + r16;
      #pragma unroll
      for (int i=0;i<4;++i){
        int n = mt*16 + kg*4 + i;
        if (n < NNQ) attn[base + (size_t)n*64 + e] = a2[nt][i]*0.125f;
      }
    }
  }
}

// ---- LIF scan on attention out -> bf16 spikes [tt,(b,n),C] ----
__global__ void k_lif_attn(const float* __restrict__ ain, const float* __restrict__ w,
                           float* __restrict__ vo, u16* __restrict__ sp, int t0, int tc){
  int g = blockIdx.x*256 + threadIdx.x;
  int e = g & 63;
  int n = (g>>6) % NNQ;
  int h = (g/(NNQ*64)) & 7;
  int b = g/(NNQ*64*8);
  size_t dst = (size_t)(b*NNQ + n)*CC + h*HD + e;
  float sg = sigm(w[0]);
  float v = (t0==0) ? 0.f : vo[g];
  for (int tt=0; tt<tc; ++tt){
    float s = lif_step(ain[(size_t)tt*PT + g], v, sg);
    sp[(size_t)tt*PT + dst] = (s!=0.f) ? 0x3F80 : 0;
  }
  vo[g] = v;
}

// ---- BN2 apply in-place on Y (proj GEMM already wrote there) ----
__global__ void k_bn2_apply(float* __restrict__ Y, const float* __restrict__ mean,
                            const float* __restrict__ rstd, const float* __restrict__ g2,
                            const float* __restrict__ b2, int t0){
  size_t idx = ((size_t)blockIdx.x*256 + threadIdx.x)*4;
  int tt = (int)(idx / PT);
  size_t off = idx - (size_t)tt*PT;
  int c = (int)(off & (CC-1));
  float4 xv = *(const float4*)&Y[idx];
  float4 mv = *(const float4*)&mean[tt*CC + c];
  float4 rv = *(const float4*)&rstd[tt*CC + c];
  float4 gv = *(const float4*)&g2[(t0+tt)*CC + c];
  float4 bv = *(const float4*)&b2[(t0+tt)*CC + c];
  float4 yv;
  yv.x = __fadd_rn(__fmul_rn(__fmul_rn(__fsub_rn(xv.x, mv.x), rv.x), gv.x), bv.x);
  yv.y = __fadd_rn(__fmul_rn(__fmul_rn(__fsub_rn(xv.y, mv.y), rv.y), gv.y), bv.y);
  yv.z = __fadd_rn(__fmul_rn(__fmul_rn(__fsub_rn(xv.z, mv.z), rv.z), gv.z), bv.z);
  yv.w = __fadd_rn(__fmul_rn(__fmul_rn(__fsub_rn(xv.w, mv.w), rv.w), gv.w), bv.w);
  *(float4*)&Y[idx] = yv;
}

extern "C" void kernel_launch(void* const* d_in, const int* in_sizes, int n_in,
                              void* d_out, int out_size, void* d_ws, size_t ws_size,
                              hipStream_t stream){
  const float* x      = (const float*)d_in[0];
  const float* qkv_w  = (const float*)d_in[1];
  const float* qkv_b  = (const float*)d_in[2];
  const float* bn1_g  = (const float*)d_in[3];
  const float* bn1_b  = (const float*)d_in[4];
  const float* proj_w = (const float*)d_in[5];
  const float* proj_b = (const float*)d_in[6];
  const float* bn2_g  = (const float*)d_in[7];
  const float* bn2_b  = (const float*)d_in[8];
  const float* w_in   = (const float*)d_in[9];
  const float* w_q    = (const float*)d_in[10];
  const float* w_k    = (const float*)d_in[11];
  const float* w_v    = (const float*)d_in[12];
  const float* w_proj = (const float*)d_in[13];
  float* outp = (float*)d_out;

  auto need = [](int tc)->size_t{
    int nmb = (tc*BN + 127)/128;
    return 4ull*5*PT + 4ull*tc*O3*2 + 4ull*tc*CC*2
         + 16ull*nmb*2*O3 + 16ull*nmb*2*CC
         + 6ull*WTOT
         + 10ull*tc*PT
         + 4ull*tc*BN*O3;
  };
  int TC = 16;
  while (TC > 1 && need(TC) > ws_size) TC >>= 1;
  int nmb = (TC*BN + 127)/128;

  char* p = (char*)d_ws;
  float* vin = (float*)p; p += 4ull*PT;
  float* vq  = (float*)p; p += 4ull*PT;
  float* vk  = (float*)p; p += 4ull*PT;
  float* vv  = (float*)p; p += 4ull*PT;
  float* vo  = (float*)p; p += 4ull*PT;
  float* mean1 = (float*)p; p += 4ull*TC*O3;
  float* rstd1 = (float*)p; p += 4ull*TC*O3;
  float* mean2 = (float*)p; p += 4ull*TC*CC;
  float* rstd2 = (float*)p; p += 4ull*TC*CC;
  double* p1sum = (double*)p; p += 8ull*nmb*2*O3;
  double* p1sq  = (double*)p; p += 8ull*nmb*2*O3;
  double* p2sum = (double*)p; p += 8ull*nmb*2*CC;
  double* p2sq  = (double*)p; p += 8ull*nmb*2*CC;
  u16* whi  = (u16*)p; p += 2ull*WTOT;
  u16* wmid = (u16*)p; p += 2ull*WTOT;
  u16* wlo  = (u16*)p; p += 2ull*WTOT;
  u16* s0    = (u16*)p; p += 2ull*TC*PT;
  u16* qsb   = (u16*)p; p += 2ull*TC*PT;
  u16* ksb   = (u16*)p; p += 2ull*TC*PT;
  u16* vsb   = (u16*)p; p += 2ull*TC*PT;
  u16* sproj = (u16*)p; p += 2ull*TC*PT;
  float* qkv_all = (float*)p;                 // tc*BN*O3 floats
  float* attn    = qkv_all;                   // tc*PT (overlaps dead qkv_all)

  k_wsplit<<<WTOT/256, 256, 0, stream>>>(qkv_w, proj_w, whi, wmid, wlo);

  for (int t0=0; t0<TT; t0+=TC){
    int M = TC*BN;
    float* outc = outp + (size_t)t0*PT;
    k_lif_x<<<PT/256, 256, 0, stream>>>(x, w_in, vin, s0, t0, TC);

    k_gemm_mfma<O3,3><<<nmb*(O3/128), 256, 0, stream>>>(
        s0, whi, wmid, wlo, qkv_b, qkv_all, p1sum, p1sq, M);

    k_stat_fold<O3><<<(TC*O3+255)/256, 256, 0, stream>>>(
        p1sum, p1sq, mean1, rstd1, nmb, TC*O3);

    k_lif_qkv<<<dim3(PT/256, 3), 256, 0, stream>>>(qkv_all, mean1, rstd1, bn1_g, bn1_b,
                                                   w_q, w_k, w_v, vq, vk, vv,
                                                   qsb, ksb, vsb, t0, TC);

    k_kvqv_mfma<<<TC*BB*HH, 256, 0, stream>>>(ksb, vsb, qsb, attn);

    k_lif_attn<<<PT/256, 256, 0, stream>>>(attn, w_proj, vo, sproj, t0, TC);

    k_gemm_mfma<CC,2><<<nmb*(CC/128), 256, 0, stream>>>(
        sproj, whi + (size_t)O3*CC, wmid + (size_t)O3*CC, wlo + (size_t)O3*CC,
        proj_b, outc, p2sum, p2sq, M);

    k_stat_fold<CC><<<(TC*CC+255)/256, 256, 0, stream>>>(
        p2sum, p2sq, mean2, rstd2, nmb, TC*CC);

    k_bn2_apply<<<(TC*(size_t)PT)/1024, 256, 0, stream>>>(outc, mean2, rstd2,
                                                          bn2_g, bn2_b, t0);
  }
}

// Round 10
// 408.458 us; speedup vs baseline: 1.0988x; 1.0988x over previous
//
#include <hip/hip_runtime.h>

// Spiking self-attention (Spikformer SSA) forward — round-7 GEMM structure
// (known-good: 128x128 MFMA, global_load_lds pre-swizzled staging, XCD swizzle,
// separate streaming BN stats), plus: proj 2-split weights, proj->d_out with
// BN2 in-place. T=16,B=8,N=196,C=512,H=8,hd=64.

#define TT 16
#define BB 8
#define NNQ 196
#define CC 512
#define HH 8
#define HD 64
#define O3 1536
#define BN (BB*NNQ)          // 1568
#define PT (BN*CC)           // 802816
#define WTOT ((O3+CC)*CC)    // 1048576 split-weight elems
#define NRG 14               // row-groups for BN stats (1568 = 14*112)

static constexpr float VTH = 0.5f;
typedef __attribute__((ext_vector_type(8))) short short8;
typedef __attribute__((ext_vector_type(4))) float f32x4;
typedef unsigned short u16;

__device__ __forceinline__ float sigm(float w){ return 1.f/(1.f+expf(-w)); }

__device__ __forceinline__ float lif_step(float x, float& v, float sg){
  float d  = __fsub_rn(x, v);
  float dd = __fmul_rn(d, sg);
  v = __fadd_rn(v, dd);
  float sp = (v >= VTH) ? 1.f : 0.f;
  v = __fmul_rn(v, __fsub_rn(1.f, sp));
  return sp;
}

__device__ __forceinline__ u16 bf16_rn(float x){
  unsigned u = __float_as_uint(x);
  unsigned r = u + 0x7FFF + ((u>>16)&1);
  return (u16)(r>>16);
}
__device__ __forceinline__ float bf16_to_f(u16 h){
  return __uint_as_float(((unsigned)h)<<16);
}

__device__ __forceinline__ void gld_lds16(const void* g, void* l){
  __builtin_amdgcn_global_load_lds(
    (const __attribute__((address_space(1))) unsigned int*)g,
    (__attribute__((address_space(3))) unsigned int*)l, 16, 0, 0);
}

// ---- split weights into hi/mid/lo bf16 ----
__global__ void k_wsplit(const float* __restrict__ qkv_w, const float* __restrict__ proj_w,
                         u16* __restrict__ whi, u16* __restrict__ wmid, u16* __restrict__ wlo){
  int i = blockIdx.x*256 + threadIdx.x;
  float w = (i < O3*CC) ? qkv_w[i] : proj_w[i - O3*CC];
  u16 h = bf16_rn(w);          float r1 = w - bf16_to_f(h);
  u16 m = bf16_rn(r1);         float r2 = r1 - bf16_to_f(m);
  u16 l = bf16_rn(r2);
  whi[i]=h; wmid[i]=m; wlo[i]=l;
}

// ---- LIF scan on input x -> bf16 spikes ----
__global__ void k_lif_x(const float* __restrict__ x, const float* __restrict__ w,
                        float* __restrict__ vin, u16* __restrict__ s0, int t0, int tc){
  int g = blockIdx.x*256 + threadIdx.x;
  float sg = sigm(w[0]);
  float v = (t0==0) ? 0.f : vin[g];
  for (int tt=0; tt<tc; ++tt){
    float sp = lif_step(x[(size_t)(t0+tt)*PT + g], v, sg);
    s0[(size_t)tt*PT + g] = (sp!=0.f) ? 0x3F80 : 0;
  }
  vin[g] = v;
}

// ---- C[M,ON] = A(bf16 0/1)*(sum of NS split weights)^T + bias, 128x128 ----
template<int ON, int NS>
__global__ __launch_bounds__(256)
void k_gemm_mfma(const u16* __restrict__ A, const u16* __restrict__ Wh,
                 const u16* __restrict__ Wm, const u16* __restrict__ Wl,
                 const float* __restrict__ bias, float* __restrict__ Cm, int M){
  __shared__ __align__(16) u16 Al[128][64];
  __shared__ __align__(16) u16 Bs[NS][128][64];
  const u16* __restrict__ Ws[3] = {Wh, Wm, Wl};
  const int nON = ON/128;
  int nwg = gridDim.x;
  int bid = blockIdx.x;
  int q = nwg >> 3, r = nwg & 7;
  int xcd = bid & 7, idx = bid >> 3;
  int wgid = (xcd < r ? xcd*(q+1) : r*(q+1) + (xcd-r)*q) + idx;
  int mb = wgid / nON, ob = wgid - mb*nON;
  int m0 = mb*128, o0 = ob*128;

  int tid = threadIdx.x;
  int w = tid>>6, lane = tid&63;
  int wm = (w&1)*64, wn = (w>>1)*64;
  int r16 = lane&15, kg = lane>>4;
  int lrow = w*32 + (lane>>3);
  int lslot = lane&7;
  f32x4 acc[4][4] = {};
  for (int k0=0;k0<512;k0+=64){
    #pragma unroll
    for (int i=0;i<4;++i){
      int row = lrow + i*8;
      int gslot = lslot ^ (row&7);
      int gr = m0+row; if (gr>=M) gr=M-1;
      gld_lds16(&A[(size_t)gr*512 + k0 + gslot*8], &Al[w*32+i*8][0]);
      #pragma unroll
      for (int sp=0; sp<NS; ++sp)
        gld_lds16(&Ws[sp][(size_t)(o0+row)*512 + k0 + gslot*8], &Bs[sp][w*32+i*8][0]);
    }
    __syncthreads();
    #pragma unroll
    for (int s=0;s<2;++s){
      short8 af[4], bfr[NS][4];
      #pragma unroll
      for (int mt=0;mt<4;++mt){
        int rr = wm + mt*16 + r16;
        af[mt] = *(const short8*)&Al[rr][((s*4+kg)^(rr&7))*8];
      }
      #pragma unroll
      for (int nt=0;nt<4;++nt){
        int rr = wn + nt*16 + r16;
        int sl = ((s*4+kg)^(rr&7))*8;
        #pragma unroll
        for (int sp=0; sp<NS; ++sp)
          bfr[sp][nt] = *(const short8*)&Bs[sp][rr][sl];
      }
      #pragma unroll
      for (int mt=0;mt<4;++mt)
        #pragma unroll
        for (int nt=0;nt<4;++nt)
          #pragma unroll
          for (int sp=0; sp<NS; ++sp)
            acc[mt][nt] = __builtin_amdgcn_mfma_f32_16x16x32_bf16(af[mt], bfr[sp][nt], acc[mt][nt],0,0,0);
    }
    __syncthreads();
  }
  #pragma unroll
  for (int mt=0; mt<4; ++mt)
    #pragma unroll
    for (int nt=0; nt<4; ++nt){
      int o = o0 + wn + nt*16 + r16;
      float bs = bias[o];
      #pragma unroll
      for (int i=0;i<4;++i){
        int m = m0 + wm + mt*16 + kg*4 + i;
        if (m < M) Cm[(size_t)m*ON + o] = acc[mt][nt][i] + bs;
      }
    }
}

// ---- BN stats stage 1: fp64 partials over 112-row groups ----
template<int O>
__global__ void k_stat_part(const float* __restrict__ X, double* __restrict__ psum,
                            double* __restrict__ psq){
  int o = blockIdx.x*64 + threadIdx.x;
  int tt = blockIdx.y;
  int rg = blockIdx.z;
  const float* Xb = X + (size_t)tt*BN*O;
  int r0 = rg*112;
  double sum=0.0, sq=0.0;
  for (int i=r0+threadIdx.y; i<r0+112; i+=4){
    double v = (double)Xb[(size_t)i*O + o];
    sum += v; sq += v*v;
  }
  __shared__ double ssum[4][64], ssq[4][64];
  ssum[threadIdx.y][threadIdx.x]=sum;
  ssq [threadIdx.y][threadIdx.x]=sq;
  __syncthreads();
  if (threadIdx.y==0){
    double s = ssum[0][threadIdx.x]+ssum[1][threadIdx.x]+ssum[2][threadIdx.x]+ssum[3][threadIdx.x];
    double q = ssq [0][threadIdx.x]+ssq [1][threadIdx.x]+ssq [2][threadIdx.x]+ssq [3][threadIdx.x];
    size_t idx = ((size_t)tt*O + o)*NRG + rg;
    psum[idx]=s; psq[idx]=q;
  }
}

// ---- BN stats stage 2: fold partials -> mean/rstd ----
template<int O, int TCN>
__global__ void k_stat_reduce(const double* __restrict__ psum, const double* __restrict__ psq,
                              float* __restrict__ mean, float* __restrict__ rstd){
  int i = blockIdx.x*256 + threadIdx.x;   // tt*O + o
  if (i >= TCN*O) return;
  double s=0.0, q=0.0;
  #pragma unroll
  for (int g=0; g<NRG; ++g){ s += psum[(size_t)i*NRG+g]; q += psq[(size_t)i*NRG+g]; }
  double m = s*(1.0/BN);
  double var = q*(1.0/BN) - m*m;
  mean[i]=(float)m;
  rstd[i]=(float)(1.0/sqrt(var+1e-5));
}

// ---- BN1 + LIF scan q/k/v -> bf16 spikes [tt,b,h,n,d] ----
__global__ void k_lif_qkv(const float* __restrict__ qkv, const float* __restrict__ mean,
                          const float* __restrict__ rstd, const float* __restrict__ g1,
                          const float* __restrict__ b1,
                          const float* __restrict__ wq, const float* __restrict__ wk,
                          const float* __restrict__ wv,
                          float* __restrict__ vq, float* __restrict__ vk, float* __restrict__ vv,
                          u16* __restrict__ qs, u16* __restrict__ ks,
                          u16* __restrict__ vs, int t0, int tc){
  int g = blockIdx.x*256 + threadIdx.x;
  int j = blockIdx.y;
  int d = g & 63;
  int n = (g>>6) % NNQ;
  int h = (g/(NNQ*64)) & 7;
  int b = g/(NNQ*64*8);
  int o = j*CC + h*HD + d;
  const float* w = (j==0)? wq : (j==1)? wk : wv;
  float* st  = (j==0)? vq : (j==1)? vk : vv;
  u16* out = (j==0)? qs : (j==1)? ks : vs;
  float sg = sigm(w[0]);
  float v = (t0==0) ? 0.f : st[g];
  size_t row = (size_t)(b*NNQ + n)*O3 + o;
  for (int tt=0; tt<tc; ++tt){
    float xv = qkv[(size_t)tt*BN*O3 + row];
    int so = tt*O3 + o;
    int go = (t0+tt)*O3 + o;
    float xn = __fadd_rn(__fmul_rn(__fmul_rn(__fsub_rn(xv, mean[so]), rstd[so]),
                                   g1[go]), b1[go]);
    float sp = lif_step(xn, v, sg);
    out[(size_t)tt*PT + g] = (sp!=0.f) ? 0x3F80 : 0;
  }
  st[g] = v;
}

// ---- per (tt,b,h): kv = K^T V (MFMA), then attn = 0.125 * Q kv (MFMA) ----
__global__ __launch_bounds__(256)
void k_kvqv_mfma(const u16* __restrict__ ks, const u16* __restrict__ vs,
                 const u16* __restrict__ qs, float* __restrict__ attn){
  __shared__ __align__(16) u16 Kb[224][64];
  __shared__ __align__(16) u16 Vb[224][64];
  __shared__ __align__(16) u16 kvb[64][64];
  int blk = blockIdx.x;
  size_t base = (size_t)blk * (NNQ*HD);
  int tid = threadIdx.x, w = tid>>6, lane = tid&63;
  int r16 = lane&15, kg = lane>>4;
  for (int u=tid; u<224*8; u+=256){
    int row=u>>3, slot=u&7;
    float4 z = {0.f,0.f,0.f,0.f};
    float4 kd = z, vd = z;
    if (row < NNQ){
      kd = *(const float4*)&ks[base + (size_t)row*64 + slot*8];
      vd = *(const float4*)&vs[base + (size_t)row*64 + slot*8];
    }
    *(float4*)&Kb[row][slot*8] = kd;
    *(float4*)&Vb[row][slot*8] = vd;
  }
  __syncthreads();
  f32x4 acc[4] = {};
  int d0 = w*16;
  for (int n0=0;n0<224;n0+=32){
    short8 af;
    #pragma unroll
    for (int jj=0;jj<8;++jj) af[jj] = (short)Kb[n0+kg*8+jj][d0 + r16];
    #pragma unroll
    for (int nt=0;nt<4;++nt){
      short8 bf;
      #pragma unroll
      for (int jj=0;jj<8;++jj) bf[jj] = (short)Vb[n0+kg*8+jj][nt*16 + r16];
      acc[nt] = __builtin_amdgcn_mfma_f32_16x16x32_bf16(af, bf, acc[nt],0,0,0);
    }
  }
  #pragma unroll
  for (int nt=0;nt<4;++nt)
    #pragma unroll
    for (int i=0;i<4;++i)
      kvb[d0 + kg*4 + i][nt*16 + r16] = (u16)(__float_as_uint(acc[nt][i])>>16);
  __syncthreads();
  for (int u=tid; u<224*8; u+=256){
    int row=u>>3, slot=u&7;
    int sl = slot ^ (row&7);
    float4 qd = {0.f,0.f,0.f,0.f};
    if (row < NNQ) qd = *(const float4*)&qs[base + (size_t)row*64 + slot*8];
    *(float4*)&Kb[row][sl*8] = qd;
  }
  __syncthreads();
  short8 bkv[2][4];
  #pragma unroll
  for (int s=0;s<2;++s)
    #pragma unroll
    for (int nt=0;nt<4;++nt){
      short8 bf;
      #pragma unroll
      for (int jj=0;jj<8;++jj) bf[jj] = (short)kvb[s*32 + kg*8 + jj][nt*16 + r16];
      bkv[s][nt] = bf;
    }
  for (int mt=w; mt<13; mt+=4){
    f32x4 a2[4] = {};
    short8 qa[2];
    #pragma unroll
    for (int s=0;s<2;++s){
      int rr = mt*16 + r16;
      qa[s] = *(const short8*)&Kb[rr][(((s*4+kg)^(rr&7)))*8];
    }
    #pragma unroll
    for (int s=0;s<2;++s)
      #pragma unroll
      for (int nt=0;nt<4;++nt)
        a2[nt] = __builtin_amdgcn_mfma_f32_16x16x32_bf16(qa[s], bkv[s][nt], a2[nt],0,0,0);
    #pragma unroll
    for (int nt=0;nt<4;++nt){
      int e = nt*16 + r16;
      #pragma unroll
      for (int i=0;i<4;++i){
        int n = mt*16 + kg*4 + i;
        if (n < NNQ) attn[base + (size_t)n*64 + e] = a2[nt][i]*0.125f;
      }
    }
  }
}

// ---- LIF scan on attention out -> bf16 spikes [tt,(b,n),C] ----
__global__ void k_lif_attn(const float* __restrict__ ain, const float* __restrict__ w,
                           float* __restrict__ vo, u16* __restrict__ sp, int t0, int tc){
  int g = blockIdx.x*256 + threadIdx.x;
  int e = g & 63;
  int n = (g>>6) % NNQ;
  int h = (g/(NNQ*64)) & 7;
  int b = g/(NNQ*64*8);
  size_t dst = (size_t)(b*NNQ + n)*CC + h*HD + e;
  float sg = sigm(w[0]);
  float v = (t0==0) ? 0.f : vo[g];
  for (int tt=0; tt<tc; ++tt){
    float s = lif_step(ain[(size_t)tt*PT + g], v, sg);
    sp[(size_t)tt*PT + dst] = (s!=0.f) ? 0x3F80 : 0;
  }
  vo[g] = v;
}

// ---- BN2 apply in-place on Y (proj GEMM already wrote there) ----
__global__ void k_bn2_apply(float* __restrict__ Y, const float* __restrict__ mean,
                            const float* __restrict__ rstd, const float* __restrict__ g2,
                            const float* __restrict__ b2, int t0){
  size_t idx = ((size_t)blockIdx.x*256 + threadIdx.x)*4;
  int tt = (int)(idx / PT);
  size_t off = idx - (size_t)tt*PT;
  int c = (int)(off & (CC-1));
  float4 xv = *(const float4*)&Y[idx];
  float4 mv = *(const float4*)&mean[tt*CC + c];
  float4 rv = *(const float4*)&rstd[tt*CC + c];
  float4 gv = *(const float4*)&g2[(t0+tt)*CC + c];
  float4 bv = *(const float4*)&b2[(t0+tt)*CC + c];
  float4 yv;
  yv.x = __fadd_rn(__fmul_rn(__fmul_rn(__fsub_rn(xv.x, mv.x), rv.x), gv.x), bv.x);
  yv.y = __fadd_rn(__fmul_rn(__fmul_rn(__fsub_rn(xv.y, mv.y), rv.y), gv.y), bv.y);
  yv.z = __fadd_rn(__fmul_rn(__fmul_rn(__fsub_rn(xv.z, mv.z), rv.z), gv.z), bv.z);
  yv.w = __fadd_rn(__fmul_rn(__fmul_rn(__fsub_rn(xv.w, mv.w), rv.w), gv.w), bv.w);
  *(float4*)&Y[idx] = yv;
}

extern "C" void kernel_launch(void* const* d_in, const int* in_sizes, int n_in,
                              void* d_out, int out_size, void* d_ws, size_t ws_size,
                              hipStream_t stream){
  const float* x      = (const float*)d_in[0];
  const float* qkv_w  = (const float*)d_in[1];
  const float* qkv_b  = (const float*)d_in[2];
  const float* bn1_g  = (const float*)d_in[3];
  const float* bn1_b  = (const float*)d_in[4];
  const float* proj_w = (const float*)d_in[5];
  const float* proj_b = (const float*)d_in[6];
  const float* bn2_g  = (const float*)d_in[7];
  const float* bn2_b  = (const float*)d_in[8];
  const float* w_in   = (const float*)d_in[9];
  const float* w_q    = (const float*)d_in[10];
  const float* w_k    = (const float*)d_in[11];
  const float* w_v    = (const float*)d_in[12];
  const float* w_proj = (const float*)d_in[13];
  float* outp = (float*)d_out;

  auto need = [](int tc)->size_t{
    return 4ull*5*PT + 8ull*tc*O3 + 8ull*tc*CC
         + 16ull*tc*O3*NRG + 16ull*tc*CC*NRG
         + 6ull*WTOT
         + 10ull*tc*PT
         + 4ull*tc*BN*O3;
  };
  int TC = 16;
  while (TC > 1 && need(TC) > ws_size) TC >>= 1;

  char* p = (char*)d_ws;
  float* vin = (float*)p; p += 4ull*PT;
  float* vq  = (float*)p; p += 4ull*PT;
  float* vk  = (float*)p; p += 4ull*PT;
  float* vv  = (float*)p; p += 4ull*PT;
  float* vo  = (float*)p; p += 4ull*PT;
  float* mean1 = (float*)p; p += 4ull*TC*O3;
  float* rstd1 = (float*)p; p += 4ull*TC*O3;
  float* mean2 = (float*)p; p += 4ull*TC*CC;
  float* rstd2 = (float*)p; p += 4ull*TC*CC;
  double* p1sum = (double*)p; p += 8ull*TC*O3*NRG;
  double* p1sq  = (double*)p; p += 8ull*TC*O3*NRG;
  double* p2sum = (double*)p; p += 8ull*TC*CC*NRG;
  double* p2sq  = (double*)p; p += 8ull*TC*CC*NRG;
  u16* whi  = (u16*)p; p += 2ull*WTOT;
  u16* wmid = (u16*)p; p += 2ull*WTOT;
  u16* wlo  = (u16*)p; p += 2ull*WTOT;
  u16* s0    = (u16*)p; p += 2ull*TC*PT;
  u16* qsb   = (u16*)p; p += 2ull*TC*PT;
  u16* ksb   = (u16*)p; p += 2ull*TC*PT;
  u16* vsb   = (u16*)p; p += 2ull*TC*PT;
  u16* sproj = (u16*)p; p += 2ull*TC*PT;
  float* qkv_all = (float*)p;                 // tc*BN*O3 floats
  float* attn    = qkv_all;                   // tc*PT (overlaps dead qkv_all)

  k_wsplit<<<WTOT/256, 256, 0, stream>>>(qkv_w, proj_w, whi, wmid, wlo);

  for (int t0=0; t0<TT; t0+=TC){
    int M = TC*BN;
    int nMB = (M+127)/128;
    float* outc = outp + (size_t)t0*PT;
    k_lif_x<<<PT/256, 256, 0, stream>>>(x, w_in, vin, s0, t0, TC);

    k_gemm_mfma<O3,3><<<nMB*(O3/128), 256, 0, stream>>>(
        s0, whi, wmid, wlo, qkv_b, qkv_all, M);

    k_stat_part<O3><<<dim3(O3/64, TC, NRG), dim3(64,4), 0, stream>>>(qkv_all, p1sum, p1sq);
    if (TC == 16)
      k_stat_reduce<O3,16><<<(16*O3+255)/256, 256, 0, stream>>>(p1sum, p1sq, mean1, rstd1);
    else if (TC == 8)
      k_stat_reduce<O3,8><<<(8*O3+255)/256, 256, 0, stream>>>(p1sum, p1sq, mean1, rstd1);
    else
      k_stat_reduce<O3,4><<<(4*O3+255)/256, 256, 0, stream>>>(p1sum, p1sq, mean1, rstd1);

    k_lif_qkv<<<dim3(PT/256, 3), 256, 0, stream>>>(qkv_all, mean1, rstd1, bn1_g, bn1_b,
                                                   w_q, w_k, w_v, vq, vk, vv,
                                                   qsb, ksb, vsb, t0, TC);

    k_kvqv_mfma<<<TC*BB*HH, 256, 0, stream>>>(ksb, vsb, qsb, attn);

    k_lif_attn<<<PT/256, 256, 0, stream>>>(attn, w_proj, vo, sproj, t0, TC);

    k_gemm_mfma<CC,2><<<nMB*(CC/128), 256, 0, stream>>>(
        sproj, whi + (size_t)O3*CC, wmid + (size_t)O3*CC, wlo + (size_t)O3*CC,
        proj_b, outc, M);

    k_stat_part<CC><<<dim3(CC/64, TC, NRG), dim3(64,4), 0, stream>>>(outc, p2sum, p2sq);
    if (TC == 16)
      k_stat_reduce<CC,16><<<(16*CC+255)/256, 256, 0, stream>>>(p2sum, p2sq, mean2, rstd2);
    else if (TC == 8)
      k_stat_reduce<CC,8><<<(8*CC+255)/256, 256, 0, stream>>>(p2sum, p2sq, mean2, rstd2);
    else
      k_stat_reduce<CC,4><<<(4*CC+255)/256, 256, 0, stream>>>(p2sum, p2sq, mean2, rstd2);

    k_bn2_apply<<<(TC*(size_t)PT)/1024, 256, 0, stream>>>(outc, mean2, rstd2,
                                                          bn2_g, bn2_b, t0);
  }
}

// Round 11
// 380.244 us; speedup vs baseline: 1.1803x; 1.0742x over previous
//
#include <hip/hip_runtime.h>

// Spiking self-attention (Spikformer SSA) forward — round-10 structure with
// all streaming kernels vectorized x4 (float4/ushort4, bit-identical math).
// 128x128 MFMA GEMMs (qkv 3-split / proj 2-split bf16 weights),
// global_load_lds pre-swizzled staging, XCD swizzle, streaming fp64 BN stats,
// proj->d_out + BN2 in-place. T=16,B=8,N=196,C=512,H=8,hd=64.

#define TT 16
#define BB 8
#define NNQ 196
#define CC 512
#define HH 8
#define HD 64
#define O3 1536
#define BN (BB*NNQ)          // 1568
#define PT (BN*CC)           // 802816
#define WTOT ((O3+CC)*CC)    // 1048576 split-weight elems
#define NRG 14               // row-groups for BN stats (1568 = 14*112)

static constexpr float VTH = 0.5f;
typedef __attribute__((ext_vector_type(8))) short short8;
typedef __attribute__((ext_vector_type(4))) float f32x4;
typedef unsigned short u16;

__device__ __forceinline__ float sigm(float w){ return 1.f/(1.f+expf(-w)); }

__device__ __forceinline__ float lif_step(float x, float& v, float sg){
  float d  = __fsub_rn(x, v);
  float dd = __fmul_rn(d, sg);
  v = __fadd_rn(v, dd);
  float sp = (v >= VTH) ? 1.f : 0.f;
  v = __fmul_rn(v, __fsub_rn(1.f, sp));
  return sp;
}

__device__ __forceinline__ u16 bf16_rn(float x){
  unsigned u = __float_as_uint(x);
  unsigned r = u + 0x7FFF + ((u>>16)&1);
  return (u16)(r>>16);
}
__device__ __forceinline__ float bf16_to_f(u16 h){
  return __uint_as_float(((unsigned)h)<<16);
}

__device__ __forceinline__ void gld_lds16(const void* g, void* l){
  __builtin_amdgcn_global_load_lds(
    (const __attribute__((address_space(1))) unsigned int*)g,
    (__attribute__((address_space(3))) unsigned int*)l, 16, 0, 0);
}

// ---- split weights into hi/mid/lo bf16 ----
__global__ void k_wsplit(const float* __restrict__ qkv_w, const float* __restrict__ proj_w,
                         u16* __restrict__ whi, u16* __restrict__ wmid, u16* __restrict__ wlo){
  int i = blockIdx.x*256 + threadIdx.x;
  float w = (i < O3*CC) ? qkv_w[i] : proj_w[i - O3*CC];
  u16 h = bf16_rn(w);          float r1 = w - bf16_to_f(h);
  u16 m = bf16_rn(r1);         float r2 = r1 - bf16_to_f(m);
  u16 l = bf16_rn(r2);
  whi[i]=h; wmid[i]=m; wlo[i]=l;
}

// ---- LIF scan on input x -> bf16 spikes (x4 vectorized) ----
__global__ void k_lif_x(const float* __restrict__ x, const float* __restrict__ w,
                        float* __restrict__ vin, u16* __restrict__ s0, int t0, int tc){
  int g4 = blockIdx.x*256 + threadIdx.x;       // vector index (4 elems)
  size_t e0 = (size_t)g4*4;
  float sg = sigm(w[0]);
  float4 v;
  if (t0==0){ v.x=0.f; v.y=0.f; v.z=0.f; v.w=0.f; }
  else v = *(const float4*)&vin[e0];
  for (int tt=0; tt<tc; ++tt){
    float4 xv = *(const float4*)&x[(size_t)(t0+tt)*PT + e0];
    ushort4 o;
    o.x = (lif_step(xv.x, v.x, sg)!=0.f) ? 0x3F80 : 0;
    o.y = (lif_step(xv.y, v.y, sg)!=0.f) ? 0x3F80 : 0;
    o.z = (lif_step(xv.z, v.z, sg)!=0.f) ? 0x3F80 : 0;
    o.w = (lif_step(xv.w, v.w, sg)!=0.f) ? 0x3F80 : 0;
    *(ushort4*)&s0[(size_t)tt*PT + e0] = o;
  }
  *(float4*)&vin[e0] = v;
}

// ---- C[M,ON] = A(bf16 0/1)*(sum of NS split weights)^T + bias, 128x128 ----
template<int ON, int NS>
__global__ __launch_bounds__(256)
void k_gemm_mfma(const u16* __restrict__ A, const u16* __restrict__ Wh,
                 const u16* __restrict__ Wm, const u16* __restrict__ Wl,
                 const float* __restrict__ bias, float* __restrict__ Cm, int M){
  __shared__ __align__(16) u16 Al[128][64];
  __shared__ __align__(16) u16 Bs[NS][128][64];
  const u16* __restrict__ Ws[3] = {Wh, Wm, Wl};
  const int nON = ON/128;
  int nwg = gridDim.x;
  int bid = blockIdx.x;
  int q = nwg >> 3, r = nwg & 7;
  int xcd = bid & 7, idx = bid >> 3;
  int wgid = (xcd < r ? xcd*(q+1) : r*(q+1) + (xcd-r)*q) + idx;
  int mb = wgid / nON, ob = wgid - mb*nON;
  int m0 = mb*128, o0 = ob*128;

  int tid = threadIdx.x;
  int w = tid>>6, lane = tid&63;
  int wm = (w&1)*64, wn = (w>>1)*64;
  int r16 = lane&15, kg = lane>>4;
  int lrow = w*32 + (lane>>3);
  int lslot = lane&7;
  f32x4 acc[4][4] = {};
  for (int k0=0;k0<512;k0+=64){
    #pragma unroll
    for (int i=0;i<4;++i){
      int row = lrow + i*8;
      int gslot = lslot ^ (row&7);
      int gr = m0+row; if (gr>=M) gr=M-1;
      gld_lds16(&A[(size_t)gr*512 + k0 + gslot*8], &Al[w*32+i*8][0]);
      #pragma unroll
      for (int sp=0; sp<NS; ++sp)
        gld_lds16(&Ws[sp][(size_t)(o0+row)*512 + k0 + gslot*8], &Bs[sp][w*32+i*8][0]);
    }
    __syncthreads();
    #pragma unroll
    for (int s=0;s<2;++s){
      short8 af[4], bfr[NS][4];
      #pragma unroll
      for (int mt=0;mt<4;++mt){
        int rr = wm + mt*16 + r16;
        af[mt] = *(const short8*)&Al[rr][((s*4+kg)^(rr&7))*8];
      }
      #pragma unroll
      for (int nt=0;nt<4;++nt){
        int rr = wn + nt*16 + r16;
        int sl = ((s*4+kg)^(rr&7))*8;
        #pragma unroll
        for (int sp=0; sp<NS; ++sp)
          bfr[sp][nt] = *(const short8*)&Bs[sp][rr][sl];
      }
      #pragma unroll
      for (int mt=0;mt<4;++mt)
        #pragma unroll
        for (int nt=0;nt<4;++nt)
          #pragma unroll
          for (int sp=0; sp<NS; ++sp)
            acc[mt][nt] = __builtin_amdgcn_mfma_f32_16x16x32_bf16(af[mt], bfr[sp][nt], acc[mt][nt],0,0,0);
    }
    __syncthreads();
  }
  #pragma unroll
  for (int mt=0; mt<4; ++mt)
    #pragma unroll
    for (int nt=0; nt<4; ++nt){
      int o = o0 + wn + nt*16 + r16;
      float bs = bias[o];
      #pragma unroll
      for (int i=0;i<4;++i){
        int m = m0 + wm + mt*16 + kg*4 + i;
        if (m < M) Cm[(size_t)m*ON + o] = acc[mt][nt][i] + bs;
      }
    }
}

// ---- BN stats stage 1: fp64 partials over 112-row groups (x4 cols/thread) ----
template<int O>
__global__ void k_stat_part(const float* __restrict__ X, double* __restrict__ psum,
                            double* __restrict__ psq){
  int o0 = (blockIdx.x*64 + threadIdx.x)*4;
  int tt = blockIdx.y;
  int rg = blockIdx.z;
  const float* Xb = X + (size_t)tt*BN*O;
  int r0 = rg*112;
  double s[4]={0,0,0,0}, qq[4]={0,0,0,0};
  for (int i=r0+threadIdx.y; i<r0+112; i+=4){
    float4 v = *(const float4*)&Xb[(size_t)i*O + o0];
    s[0]+=(double)v.x; qq[0]+=(double)v.x*(double)v.x;
    s[1]+=(double)v.y; qq[1]+=(double)v.y*(double)v.y;
    s[2]+=(double)v.z; qq[2]+=(double)v.z*(double)v.z;
    s[3]+=(double)v.w; qq[3]+=(double)v.w*(double)v.w;
  }
  __shared__ double ssum[4][64][4], ssq[4][64][4];
  #pragma unroll
  for (int c=0;c<4;++c){
    ssum[threadIdx.y][threadIdx.x][c]=s[c];
    ssq [threadIdx.y][threadIdx.x][c]=qq[c];
  }
  __syncthreads();
  if (threadIdx.y==0){
    #pragma unroll
    for (int c=0;c<4;++c){
      double sv = ssum[0][threadIdx.x][c]+ssum[1][threadIdx.x][c]
                + ssum[2][threadIdx.x][c]+ssum[3][threadIdx.x][c];
      double qv = ssq[0][threadIdx.x][c]+ssq[1][threadIdx.x][c]
                + ssq[2][threadIdx.x][c]+ssq[3][threadIdx.x][c];
      size_t idx = ((size_t)tt*O + o0 + c)*NRG + rg;
      psum[idx]=sv; psq[idx]=qv;
    }
  }
}

// ---- BN stats stage 2: fold partials -> mean/rstd ----
template<int O, int TCN>
__global__ void k_stat_reduce(const double* __restrict__ psum, const double* __restrict__ psq,
                              float* __restrict__ mean, float* __restrict__ rstd){
  int i = blockIdx.x*256 + threadIdx.x;   // tt*O + o
  if (i >= TCN*O) return;
  double s=0.0, q=0.0;
  #pragma unroll
  for (int g=0; g<NRG; ++g){ s += psum[(size_t)i*NRG+g]; q += psq[(size_t)i*NRG+g]; }
  double m = s*(1.0/BN);
  double var = q*(1.0/BN) - m*m;
  mean[i]=(float)m;
  rstd[i]=(float)(1.0/sqrt(var+1e-5));
}

// ---- BN1 + LIF scan q/k/v -> bf16 spikes [tt,b,h,n,d] (x4 over d) ----
__global__ void k_lif_qkv(const float* __restrict__ qkv, const float* __restrict__ mean,
                          const float* __restrict__ rstd, const float* __restrict__ g1,
                          const float* __restrict__ b1,
                          const float* __restrict__ wq, const float* __restrict__ wk,
                          const float* __restrict__ wv,
                          float* __restrict__ vq, float* __restrict__ vk, float* __restrict__ vv,
                          u16* __restrict__ qs, u16* __restrict__ ks,
                          u16* __restrict__ vs, int t0, int tc){
  int g4 = blockIdx.x*256 + threadIdx.x;   // 4 consecutive d
  int j = blockIdx.y;
  int d = (g4 & 15)*4;
  int n = (g4>>4) % NNQ;
  int h = (g4/(NNQ*16)) & 7;
  int b = g4/(NNQ*16*8);
  int o = j*CC + h*HD + d;
  const float* w = (j==0)? wq : (j==1)? wk : wv;
  float* st  = (j==0)? vq : (j==1)? vk : vv;
  u16* out = (j==0)? qs : (j==1)? ks : vs;
  float sg = sigm(w[0]);
  size_t e0 = (size_t)g4*4;
  float4 v;
  if (t0==0){ v.x=0.f; v.y=0.f; v.z=0.f; v.w=0.f; }
  else v = *(const float4*)&st[e0];
  size_t row = (size_t)(b*NNQ + n)*O3 + o;
  for (int tt=0; tt<tc; ++tt){
    float4 xv = *(const float4*)&qkv[(size_t)tt*BN*O3 + row];
    int so = tt*O3 + o;
    int go = (t0+tt)*O3 + o;
    float4 mv = *(const float4*)&mean[so];
    float4 rv = *(const float4*)&rstd[so];
    float4 gv = *(const float4*)&g1[go];
    float4 bv = *(const float4*)&b1[go];
    ushort4 ov;
    {
      float xn = __fadd_rn(__fmul_rn(__fmul_rn(__fsub_rn(xv.x, mv.x), rv.x), gv.x), bv.x);
      ov.x = (lif_step(xn, v.x, sg)!=0.f) ? 0x3F80 : 0;
    }{
      float xn = __fadd_rn(__fmul_rn(__fmul_rn(__fsub_rn(xv.y, mv.y), rv.y), gv.y), bv.y);
      ov.y = (lif_step(xn, v.y, sg)!=0.f) ? 0x3F80 : 0;
    }{
      float xn = __fadd_rn(__fmul_rn(__fmul_rn(__fsub_rn(xv.z, mv.z), rv.z), gv.z), bv.z);
      ov.z = (lif_step(xn, v.z, sg)!=0.f) ? 0x3F80 : 0;
    }{
      float xn = __fadd_rn(__fmul_rn(__fmul_rn(__fsub_rn(xv.w, mv.w), rv.w), gv.w), bv.w);
      ov.w = (lif_step(xn, v.w, sg)!=0.f) ? 0x3F80 : 0;
    }
    *(ushort4*)&out[(size_t)tt*PT + e0] = ov;
  }
  *(float4*)&st[e0] = v;
}

// ---- per (tt,b,h): kv = K^T V (MFMA), then attn = 0.125 * Q kv (MFMA) ----
__global__ __launch_bounds__(256)
void k_kvqv_mfma(const u16* __restrict__ ks, const u16* __restrict__ vs,
                 const u16* __restrict__ qs, float* __restrict__ attn){
  __shared__ __align__(16) u16 Kb[224][64];
  __shared__ __align__(16) u16 Vb[224][64];
  __shared__ __align__(16) u16 kvb[64][64];
  int blk = blockIdx.x;
  size_t base = (size_t)blk * (NNQ*HD);
  int tid = threadIdx.x, w = tid>>6, lane = tid&63;
  int r16 = lane&15, kg = lane>>4;
  for (int u=tid; u<224*8; u+=256){
    int row=u>>3, slot=u&7;
    float4 z = {0.f,0.f,0.f,0.f};
    float4 kd = z, vd = z;
    if (row < NNQ){
      kd = *(const float4*)&ks[base + (size_t)row*64 + slot*8];
      vd = *(const float4*)&vs[base + (size_t)row*64 + slot*8];
    }
    *(float4*)&Kb[row][slot*8] = kd;
    *(float4*)&Vb[row][slot*8] = vd;
  }
  __syncthreads();
  f32x4 acc[4] = {};
  int d0 = w*16;
  for (int n0=0;n0<224;n0+=32){
    short8 af;
    #pragma unroll
    for (int jj=0;jj<8;++jj) af[jj] = (short)Kb[n0+kg*8+jj][d0 + r16];
    #pragma unroll
    for (int nt=0;nt<4;++nt){
      short8 bf;
      #pragma unroll
      for (int jj=0;jj<8;++jj) bf[jj] = (short)Vb[n0+kg*8+jj][nt*16 + r16];
      acc[nt] = __builtin_amdgcn_mfma_f32_16x16x32_bf16(af, bf, acc[nt],0,0,0);
    }
  }
  #pragma unroll
  for (int nt=0;nt<4;++nt)
    #pragma unroll
    for (int i=0;i<4;++i)
      kvb[d0 + kg*4 + i][nt*16 + r16] = (u16)(__float_as_uint(acc[nt][i])>>16);
  __syncthreads();
  for (int u=tid; u<224*8; u+=256){
    int row=u>>3, slot=u&7;
    int sl = slot ^ (row&7);
    float4 qd = {0.f,0.f,0.f,0.f};
    if (row < NNQ) qd = *(const float4*)&qs[base + (size_t)row*64 + slot*8];
    *(float4*)&Kb[row][sl*8] = qd;
  }
  __syncthreads();
  short8 bkv[2][4];
  #pragma unroll
  for (int s=0;s<2;++s)
    #pragma unroll
    for (int nt=0;nt<4;++nt){
      short8 bf;
      #pragma unroll
      for (int jj=0;jj<8;++jj) bf[jj] = (short)kvb[s*32 + kg*8 + jj][nt*16 + r16];
      bkv[s][nt] = bf;
    }
  for (int mt=w; mt<13; mt+=4){
    f32x4 a2[4] = {};
    short8 qa[2];
    #pragma unroll
    for (int s=0;s<2;++s){
      int rr = mt*16 + r16;
      qa[s] = *(const short8*)&Kb[rr][(((s*4+kg)^(rr&7)))*8];
    }
    #pragma unroll
    for (int s=0;s<2;++s)
      #pragma unroll
      for (int nt=0;nt<4;++nt)
        a2[nt] = __builtin_amdgcn_mfma_f32_16x16x32_bf16(qa[s], bkv[s][nt], a2[nt],0,0,0);
    #pragma unroll
    for (int nt=0;nt<4;++nt){
      int e = nt*16 + r16;
      #pragma unroll
      for (int i=0;i<4;++i){
        int n = mt*16 + kg*4 + i;
        if (n < NNQ) attn[base + (size_t)n*64 + e] = a2[nt][i]*0.125f;
      }
    }
  }
}

// ---- LIF scan on attention out -> bf16 spikes [tt,(b,n),C] (x4 over e) ----
__global__ void k_lif_attn(const float* __restrict__ ain, const float* __restrict__ w,
                           float* __restrict__ vo, u16* __restrict__ sp, int t0, int tc){
  int g4 = blockIdx.x*256 + threadIdx.x;
  int e = (g4 & 15)*4;
  int n = (g4>>4) % NNQ;
  int h = (g4/(NNQ*16)) & 7;
  int b = g4/(NNQ*16*8);
  size_t e0 = (size_t)g4*4;
  size_t dst = (size_t)(b*NNQ + n)*CC + h*HD + e;
  float sg = sigm(w[0]);
  float4 v;
  if (t0==0){ v.x=0.f; v.y=0.f; v.z=0.f; v.w=0.f; }
  else v = *(const float4*)&vo[e0];
  for (int tt=0; tt<tc; ++tt){
    float4 xv = *(const float4*)&ain[(size_t)tt*PT + e0];
    ushort4 ov;
    ov.x = (lif_step(xv.x, v.x, sg)!=0.f) ? 0x3F80 : 0;
    ov.y = (lif_step(xv.y, v.y, sg)!=0.f) ? 0x3F80 : 0;
    ov.z = (lif_step(xv.z, v.z, sg)!=0.f) ? 0x3F80 : 0;
    ov.w = (lif_step(xv.w, v.w, sg)!=0.f) ? 0x3F80 : 0;
    *(ushort4*)&sp[(size_t)tt*PT + dst] = ov;
  }
  *(float4*)&vo[e0] = v;
}

// ---- BN2 apply in-place on Y (proj GEMM already wrote there) ----
__global__ void k_bn2_apply(float* __restrict__ Y, const float* __restrict__ mean,
                            const float* __restrict__ rstd, const float* __restrict__ g2,
                            const float* __restrict__ b2, int t0){
  size_t idx = ((size_t)blockIdx.x*256 + threadIdx.x)*4;
  int tt = (int)(idx / PT);
  size_t off = idx - (size_t)tt*PT;
  int c = (int)(off & (CC-1));
  float4 xv = *(const float4*)&Y[idx];
  float4 mv = *(const float4*)&mean[tt*CC + c];
  float4 rv = *(const float4*)&rstd[tt*CC + c];
  float4 gv = *(const float4*)&g2[(t0+tt)*CC + c];
  float4 bv = *(const float4*)&b2[(t0+tt)*CC + c];
  float4 yv;
  yv.x = __fadd_rn(__fmul_rn(__fmul_rn(__fsub_rn(xv.x, mv.x), rv.x), gv.x), bv.x);
  yv.y = __fadd_rn(__fmul_rn(__fmul_rn(__fsub_rn(xv.y, mv.y), rv.y), gv.y), bv.y);
  yv.z = __fadd_rn(__fmul_rn(__fmul_rn(__fsub_rn(xv.z, mv.z), rv.z), gv.z), bv.z);
  yv.w = __fadd_rn(__fmul_rn(__fmul_rn(__fsub_rn(xv.w, mv.w), rv.w), gv.w), bv.w);
  *(float4*)&Y[idx] = yv;
}

extern "C" void kernel_launch(void* const* d_in, const int* in_sizes, int n_in,
                              void* d_out, int out_size, void* d_ws, size_t ws_size,
                              hipStream_t stream){
  const float* x      = (const float*)d_in[0];
  const float* qkv_w  = (const float*)d_in[1];
  const float* qkv_b  = (const float*)d_in[2];
  const float* bn1_g  = (const float*)d_in[3];
  const float* bn1_b  = (const float*)d_in[4];
  const float* proj_w = (const float*)d_in[5];
  const float* proj_b = (const float*)d_in[6];
  const float* bn2_g  = (const float*)d_in[7];
  const float* bn2_b  = (const float*)d_in[8];
  const float* w_in   = (const float*)d_in[9];
  const float* w_q    = (const float*)d_in[10];
  const float* w_k    = (const float*)d_in[11];
  const float* w_v    = (const float*)d_in[12];
  const float* w_proj = (const float*)d_in[13];
  float* outp = (float*)d_out;

  auto need = [](int tc)->size_t{
    return 4ull*5*PT + 8ull*tc*O3 + 8ull*tc*CC
         + 16ull*tc*O3*NRG + 16ull*tc*CC*NRG
         + 6ull*WTOT
         + 10ull*tc*PT
         + 4ull*tc*BN*O3;
  };
  int TC = 16;
  while (TC > 1 && need(TC) > ws_size) TC >>= 1;

  char* p = (char*)d_ws;
  float* vin = (float*)p; p += 4ull*PT;
  float* vq  = (float*)p; p += 4ull*PT;
  float* vk  = (float*)p; p += 4ull*PT;
  float* vv  = (float*)p; p += 4ull*PT;
  float* vo  = (float*)p; p += 4ull*PT;
  float* mean1 = (float*)p; p += 4ull*TC*O3;
  float* rstd1 = (float*)p; p += 4ull*TC*O3;
  float* mean2 = (float*)p; p += 4ull*TC*CC;
  float* rstd2 = (float*)p; p += 4ull*TC*CC;
  double* p1sum = (double*)p; p += 8ull*TC*O3*NRG;
  double* p1sq  = (double*)p; p += 8ull*TC*O3*NRG;
  double* p2sum = (double*)p; p += 8ull*TC*CC*NRG;
  double* p2sq  = (double*)p; p += 8ull*TC*CC*NRG;
  u16* whi  = (u16*)p; p += 2ull*WTOT;
  u16* wmid = (u16*)p; p += 2ull*WTOT;
  u16* wlo  = (u16*)p; p += 2ull*WTOT;
  u16* s0    = (u16*)p; p += 2ull*TC*PT;
  u16* qsb   = (u16*)p; p += 2ull*TC*PT;
  u16* ksb   = (u16*)p; p += 2ull*TC*PT;
  u16* vsb   = (u16*)p; p += 2ull*TC*PT;
  u16* sproj = (u16*)p; p += 2ull*TC*PT;
  float* qkv_all = (float*)p;                 // tc*BN*O3 floats
  float* attn    = qkv_all;                   // tc*PT (overlaps dead qkv_all)

  k_wsplit<<<WTOT/256, 256, 0, stream>>>(qkv_w, proj_w, whi, wmid, wlo);

  for (int t0=0; t0<TT; t0+=TC){
    int M = TC*BN;
    int nMB = (M+127)/128;
    float* outc = outp + (size_t)t0*PT;
    k_lif_x<<<PT/1024, 256, 0, stream>>>(x, w_in, vin, s0, t0, TC);

    k_gemm_mfma<O3,3><<<nMB*(O3/128), 256, 0, stream>>>(
        s0, whi, wmid, wlo, qkv_b, qkv_all, M);

    k_stat_part<O3><<<dim3(O3/256, TC, NRG), dim3(64,4), 0, stream>>>(qkv_all, p1sum, p1sq);
    if (TC == 16)
      k_stat_reduce<O3,16><<<(16*O3+255)/256, 256, 0, stream>>>(p1sum, p1sq, mean1, rstd1);
    else if (TC == 8)
      k_stat_reduce<O3,8><<<(8*O3+255)/256, 256, 0, stream>>>(p1sum, p1sq, mean1, rstd1);
    else
      k_stat_reduce<O3,4><<<(4*O3+255)/256, 256, 0, stream>>>(p1sum, p1sq, mean1, rstd1);

    k_lif_qkv<<<dim3(PT/1024, 3), 256, 0, stream>>>(qkv_all, mean1, rstd1, bn1_g, bn1_b,
                                                    w_q, w_k, w_v, vq, vk, vv,
                                                    qsb, ksb, vsb, t0, TC);

    k_kvqv_mfma<<<TC*BB*HH, 256, 0, stream>>>(ksb, vsb, qsb, attn);

    k_lif_attn<<<PT/1024, 256, 0, stream>>>(attn, w_proj, vo, sproj, t0, TC);

    k_gemm_mfma<CC,2><<<nMB*(CC/128), 256, 0, stream>>>(
        sproj, whi + (size_t)O3*CC, wmid + (size_t)O3*CC, wlo + (size_t)O3*CC,
        proj_b, outc, M);

    k_stat_part<CC><<<dim3(CC/256, TC, NRG), dim3(64,4), 0, stream>>>(outc, p2sum, p2sq);
    if (TC == 16)
      k_stat_reduce<CC,16><<<(16*CC+255)/256, 256, 0, stream>>>(p2sum, p2sq, mean2, rstd2);
    else if (TC == 8)
      k_stat_reduce<CC,8><<<(8*CC+255)/256, 256, 0, stream>>>(p2sum, p2sq, mean2, rstd2);
    else
      k_stat_reduce<CC,4><<<(4*CC+255)/256, 256, 0, stream>>>(p2sum, p2sq, mean2, rstd2);

    k_bn2_apply<<<(TC*(size_t)PT)/1024, 256, 0, stream>>>(outc, mean2, rstd2,
                                                          bn2_g, bn2_b, t0);
  }
}

// Round 12
// 373.455 us; speedup vs baseline: 1.2018x; 1.0182x over previous
//
#include <hip/hip_runtime.h>

// Spiking self-attention (Spikformer SSA) forward — round-11 structure plus
// bank-conflict-free k_kvqv (col-XOR swizzle on K/V/kv LDS tiles; bit-identical
// values). 128x128 MFMA GEMMs (qkv 3-split / proj 2-split bf16 weights),
// global_load_lds pre-swizzled staging, XCD swizzle, streaming fp64 BN stats,
// x4-vectorized streaming kernels, proj->d_out + BN2 in-place.
// T=16,B=8,N=196,C=512,H=8,hd=64.

#define TT 16
#define BB 8
#define NNQ 196
#define CC 512
#define HH 8
#define HD 64
#define O3 1536
#define BN (BB*NNQ)          // 1568
#define PT (BN*CC)           // 802816
#define WTOT ((O3+CC)*CC)    // 1048576 split-weight elems
#define NRG 14               // row-groups for BN stats (1568 = 14*112)

static constexpr float VTH = 0.5f;
typedef __attribute__((ext_vector_type(8))) short short8;
typedef __attribute__((ext_vector_type(4))) float f32x4;
typedef unsigned short u16;

__device__ __forceinline__ float sigm(float w){ return 1.f/(1.f+expf(-w)); }

__device__ __forceinline__ float lif_step(float x, float& v, float sg){
  float d  = __fsub_rn(x, v);
  float dd = __fmul_rn(d, sg);
  v = __fadd_rn(v, dd);
  float sp = (v >= VTH) ? 1.f : 0.f;
  v = __fmul_rn(v, __fsub_rn(1.f, sp));
  return sp;
}

__device__ __forceinline__ u16 bf16_rn(float x){
  unsigned u = __float_as_uint(x);
  unsigned r = u + 0x7FFF + ((u>>16)&1);
  return (u16)(r>>16);
}
__device__ __forceinline__ float bf16_to_f(u16 h){
  return __uint_as_float(((unsigned)h)<<16);
}

__device__ __forceinline__ void gld_lds16(const void* g, void* l){
  __builtin_amdgcn_global_load_lds(
    (const __attribute__((address_space(1))) unsigned int*)g,
    (__attribute__((address_space(3))) unsigned int*)l, 16, 0, 0);
}

// ---- split weights into hi/mid/lo bf16 ----
__global__ void k_wsplit(const float* __restrict__ qkv_w, const float* __restrict__ proj_w,
                         u16* __restrict__ whi, u16* __restrict__ wmid, u16* __restrict__ wlo){
  int i = blockIdx.x*256 + threadIdx.x;
  float w = (i < O3*CC) ? qkv_w[i] : proj_w[i - O3*CC];
  u16 h = bf16_rn(w);          float r1 = w - bf16_to_f(h);
  u16 m = bf16_rn(r1);         float r2 = r1 - bf16_to_f(m);
  u16 l = bf16_rn(r2);
  whi[i]=h; wmid[i]=m; wlo[i]=l;
}

// ---- LIF scan on input x -> bf16 spikes (x4 vectorized) ----
__global__ void k_lif_x(const float* __restrict__ x, const float* __restrict__ w,
                        float* __restrict__ vin, u16* __restrict__ s0, int t0, int tc){
  int g4 = blockIdx.x*256 + threadIdx.x;       // vector index (4 elems)
  size_t e0 = (size_t)g4*4;
  float sg = sigm(w[0]);
  float4 v;
  if (t0==0){ v.x=0.f; v.y=0.f; v.z=0.f; v.w=0.f; }
  else v = *(const float4*)&vin[e0];
  for (int tt=0; tt<tc; ++tt){
    float4 xv = *(const float4*)&x[(size_t)(t0+tt)*PT + e0];
    ushort4 o;
    o.x = (lif_step(xv.x, v.x, sg)!=0.f) ? 0x3F80 : 0;
    o.y = (lif_step(xv.y, v.y, sg)!=0.f) ? 0x3F80 : 0;
    o.z = (lif_step(xv.z, v.z, sg)!=0.f) ? 0x3F80 : 0;
    o.w = (lif_step(xv.w, v.w, sg)!=0.f) ? 0x3F80 : 0;
    *(ushort4*)&s0[(size_t)tt*PT + e0] = o;
  }
  *(float4*)&vin[e0] = v;
}

// ---- C[M,ON] = A(bf16 0/1)*(sum of NS split weights)^T + bias, 128x128 ----
template<int ON, int NS>
__global__ __launch_bounds__(256)
void k_gemm_mfma(const u16* __restrict__ A, const u16* __restrict__ Wh,
                 const u16* __restrict__ Wm, const u16* __restrict__ Wl,
                 const float* __restrict__ bias, float* __restrict__ Cm, int M){
  __shared__ __align__(16) u16 Al[128][64];
  __shared__ __align__(16) u16 Bs[NS][128][64];
  const u16* __restrict__ Ws[3] = {Wh, Wm, Wl};
  const int nON = ON/128;
  int nwg = gridDim.x;
  int bid = blockIdx.x;
  int q = nwg >> 3, r = nwg & 7;
  int xcd = bid & 7, idx = bid >> 3;
  int wgid = (xcd < r ? xcd*(q+1) : r*(q+1) + (xcd-r)*q) + idx;
  int mb = wgid / nON, ob = wgid - mb*nON;
  int m0 = mb*128, o0 = ob*128;

  int tid = threadIdx.x;
  int w = tid>>6, lane = tid&63;
  int wm = (w&1)*64, wn = (w>>1)*64;
  int r16 = lane&15, kg = lane>>4;
  int lrow = w*32 + (lane>>3);
  int lslot = lane&7;
  f32x4 acc[4][4] = {};
  for (int k0=0;k0<512;k0+=64){
    #pragma unroll
    for (int i=0;i<4;++i){
      int row = lrow + i*8;
      int gslot = lslot ^ (row&7);
      int gr = m0+row; if (gr>=M) gr=M-1;
      gld_lds16(&A[(size_t)gr*512 + k0 + gslot*8], &Al[w*32+i*8][0]);
      #pragma unroll
      for (int sp=0; sp<NS; ++sp)
        gld_lds16(&Ws[sp][(size_t)(o0+row)*512 + k0 + gslot*8], &Bs[sp][w*32+i*8][0]);
    }
    __syncthreads();
    #pragma unroll
    for (int s=0;s<2;++s){
      short8 af[4], bfr[NS][4];
      #pragma unroll
      for (int mt=0;mt<4;++mt){
        int rr = wm + mt*16 + r16;
        af[mt] = *(const short8*)&Al[rr][((s*4+kg)^(rr&7))*8];
      }
      #pragma unroll
      for (int nt=0;nt<4;++nt){
        int rr = wn + nt*16 + r16;
        int sl = ((s*4+kg)^(rr&7))*8;
        #pragma unroll
        for (int sp=0; sp<NS; ++sp)
          bfr[sp][nt] = *(const short8*)&Bs[sp][rr][sl];
      }
      #pragma unroll
      for (int mt=0;mt<4;++mt)
        #pragma unroll
        for (int nt=0;nt<4;++nt)
          #pragma unroll
          for (int sp=0; sp<NS; ++sp)
            acc[mt][nt] = __builtin_amdgcn_mfma_f32_16x16x32_bf16(af[mt], bfr[sp][nt], acc[mt][nt],0,0,0);
    }
    __syncthreads();
  }
  #pragma unroll
  for (int mt=0; mt<4; ++mt)
    #pragma unroll
    for (int nt=0; nt<4; ++nt){
      int o = o0 + wn + nt*16 + r16;
      float bs = bias[o];
      #pragma unroll
      for (int i=0;i<4;++i){
        int m = m0 + wm + mt*16 + kg*4 + i;
        if (m < M) Cm[(size_t)m*ON + o] = acc[mt][nt][i] + bs;
      }
    }
}

// ---- BN stats stage 1: fp64 partials over 112-row groups (x4 cols/thread) ----
template<int O>
__global__ void k_stat_part(const float* __restrict__ X, double* __restrict__ psum,
                            double* __restrict__ psq){
  int o0 = (blockIdx.x*64 + threadIdx.x)*4;
  int tt = blockIdx.y;
  int rg = blockIdx.z;
  const float* Xb = X + (size_t)tt*BN*O;
  int r0 = rg*112;
  double s[4]={0,0,0,0}, qq[4]={0,0,0,0};
  for (int i=r0+threadIdx.y; i<r0+112; i+=4){
    float4 v = *(const float4*)&Xb[(size_t)i*O + o0];
    s[0]+=(double)v.x; qq[0]+=(double)v.x*(double)v.x;
    s[1]+=(double)v.y; qq[1]+=(double)v.y*(double)v.y;
    s[2]+=(double)v.z; qq[2]+=(double)v.z*(double)v.z;
    s[3]+=(double)v.w; qq[3]+=(double)v.w*(double)v.w;
  }
  __shared__ double ssum[4][64][4], ssq[4][64][4];
  #pragma unroll
  for (int c=0;c<4;++c){
    ssum[threadIdx.y][threadIdx.x][c]=s[c];
    ssq [threadIdx.y][threadIdx.x][c]=qq[c];
  }
  __syncthreads();
  if (threadIdx.y==0){
    #pragma unroll
    for (int c=0;c<4;++c){
      double sv = ssum[0][threadIdx.x][c]+ssum[1][threadIdx.x][c]
                + ssum[2][threadIdx.x][c]+ssum[3][threadIdx.x][c];
      double qv = ssq[0][threadIdx.x][c]+ssq[1][threadIdx.x][c]
                + ssq[2][threadIdx.x][c]+ssq[3][threadIdx.x][c];
      size_t idx = ((size_t)tt*O + o0 + c)*NRG + rg;
      psum[idx]=sv; psq[idx]=qv;
    }
  }
}

// ---- BN stats stage 2: fold partials -> mean/rstd ----
template<int O, int TCN>
__global__ void k_stat_reduce(const double* __restrict__ psum, const double* __restrict__ psq,
                              float* __restrict__ mean, float* __restrict__ rstd){
  int i = blockIdx.x*256 + threadIdx.x;   // tt*O + o
  if (i >= TCN*O) return;
  double s=0.0, q=0.0;
  #pragma unroll
  for (int g=0; g<NRG; ++g){ s += psum[(size_t)i*NRG+g]; q += psq[(size_t)i*NRG+g]; }
  double m = s*(1.0/BN);
  double var = q*(1.0/BN) - m*m;
  mean[i]=(float)m;
  rstd[i]=(float)(1.0/sqrt(var+1e-5));
}

// ---- BN1 + LIF scan q/k/v -> bf16 spikes [tt,b,h,n,d] (x4 over d) ----
__global__ void k_lif_qkv(const float* __restrict__ qkv, const float* __restrict__ mean,
                          const float* __restrict__ rstd, const float* __restrict__ g1,
                          const float* __restrict__ b1,
                          const float* __restrict__ wq, const float* __restrict__ wk,
                          const float* __restrict__ wv,
                          float* __restrict__ vq, float* __restrict__ vk, float* __restrict__ vv,
                          u16* __restrict__ qs, u16* __restrict__ ks,
                          u16* __restrict__ vs, int t0, int tc){
  int g4 = blockIdx.x*256 + threadIdx.x;   // 4 consecutive d
  int j = blockIdx.y;
  int d = (g4 & 15)*4;
  int n = (g4>>4) % NNQ;
  int h = (g4/(NNQ*16)) & 7;
  int b = g4/(NNQ*16*8);
  int o = j*CC + h*HD + d;
  const float* w = (j==0)? wq : (j==1)? wk : wv;
  float* st  = (j==0)? vq : (j==1)? vk : vv;
  u16* out = (j==0)? qs : (j==1)? ks : vs;
  float sg = sigm(w[0]);
  size_t e0 = (size_t)g4*4;
  float4 v;
  if (t0==0){ v.x=0.f; v.y=0.f; v.z=0.f; v.w=0.f; }
  else v = *(const float4*)&st[e0];
  size_t row = (size_t)(b*NNQ + n)*O3 + o;
  for (int tt=0; tt<tc; ++tt){
    float4 xv = *(const float4*)&qkv[(size_t)tt*BN*O3 + row];
    int so = tt*O3 + o;
    int go = (t0+tt)*O3 + o;
    float4 mv = *(const float4*)&mean[so];
    float4 rv = *(const float4*)&rstd[so];
    float4 gv = *(const float4*)&g1[go];
    float4 bv = *(const float4*)&b1[go];
    ushort4 ov;
    {
      float xn = __fadd_rn(__fmul_rn(__fmul_rn(__fsub_rn(xv.x, mv.x), rv.x), gv.x), bv.x);
      ov.x = (lif_step(xn, v.x, sg)!=0.f) ? 0x3F80 : 0;
    }{
      float xn = __fadd_rn(__fmul_rn(__fmul_rn(__fsub_rn(xv.y, mv.y), rv.y), gv.y), bv.y);
      ov.y = (lif_step(xn, v.y, sg)!=0.f) ? 0x3F80 : 0;
    }{
      float xn = __fadd_rn(__fmul_rn(__fmul_rn(__fsub_rn(xv.z, mv.z), rv.z), gv.z), bv.z);
      ov.z = (lif_step(xn, v.z, sg)!=0.f) ? 0x3F80 : 0;
    }{
      float xn = __fadd_rn(__fmul_rn(__fmul_rn(__fsub_rn(xv.w, mv.w), rv.w), gv.w), bv.w);
      ov.w = (lif_step(xn, v.w, sg)!=0.f) ? 0x3F80 : 0;
    }
    *(ushort4*)&out[(size_t)tt*PT + e0] = ov;
  }
  *(float4*)&st[e0] = v;
}

// ---- per (tt,b,h): kv = K^T V (MFMA), then attn = 0.125 * Q kv (MFMA) ----
// K/V/kv LDS tiles col-XOR-swizzled: elem(row,col) at [row][col ^ (((row>>3)&3)<<4)]
// -> fragment reads (rows stride 8 per kg-group) spread over all 32 banks.
__global__ __launch_bounds__(256)
void k_kvqv_mfma(const u16* __restrict__ ks, const u16* __restrict__ vs,
                 const u16* __restrict__ qs, float* __restrict__ attn){
  __shared__ __align__(16) u16 Kb[224][64];
  __shared__ __align__(16) u16 Vb[224][64];
  __shared__ __align__(16) u16 kvb[64][64];
  int blk = blockIdx.x;
  size_t base = (size_t)blk * (NNQ*HD);
  int tid = threadIdx.x, w = tid>>6, lane = tid&63;
  int r16 = lane&15, kg = lane>>4;
  // stage K,V (zero-pad rows 196..223), col-swizzled at float4 (8-u16) granularity
  for (int u=tid; u<224*8; u+=256){
    int row=u>>3, slot=u&7;
    int sl = slot ^ (((row>>3)&3)<<1);
    float4 z = {0.f,0.f,0.f,0.f};
    float4 kd = z, vd = z;
    if (row < NNQ){
      kd = *(const float4*)&ks[base + (size_t)row*64 + slot*8];
      vd = *(const float4*)&vs[base + (size_t)row*64 + slot*8];
    }
    *(float4*)&Kb[row][sl*8] = kd;
    *(float4*)&Vb[row][sl*8] = vd;
  }
  __syncthreads();
  // phase 1: kv[d][e] = sum_n K[n][d] V[n][e]; wave w owns d-tile w
  f32x4 acc[4] = {};
  int d0 = w*16;
  for (int n0=0;n0<224;n0+=32){
    int sw = (((n0 + kg*8)>>3)&3)<<4;     // constant over jj (8-aligned row group)
    short8 af;
    #pragma unroll
    for (int jj=0;jj<8;++jj) af[jj] = (short)Kb[n0+kg*8+jj][(d0 + r16) ^ sw];
    #pragma unroll
    for (int nt=0;nt<4;++nt){
      short8 bf;
      #pragma unroll
      for (int jj=0;jj<8;++jj) bf[jj] = (short)Vb[n0+kg*8+jj][(nt*16 + r16) ^ sw];
      acc[nt] = __builtin_amdgcn_mfma_f32_16x16x32_bf16(af, bf, acc[nt],0,0,0);
    }
  }
  // kv -> bf16 in LDS (exact ints <= 196), swizzled by d-row-group
  #pragma unroll
  for (int nt=0;nt<4;++nt)
    #pragma unroll
    for (int i=0;i<4;++i){
      int d = d0 + kg*4 + i;
      kvb[d][(nt*16 + r16) ^ (((d>>3)&3)<<4)] = (u16)(__float_as_uint(acc[nt][i])>>16);
    }
  __syncthreads();
  // stage Q into Kb, GEMM-style row-XOR swizzle (b128 frag reads, rows stride 16)
  for (int u=tid; u<224*8; u+=256){
    int row=u>>3, slot=u&7;
    int sl = slot ^ (row&7);
    float4 qd = {0.f,0.f,0.f,0.f};
    if (row < NNQ) qd = *(const float4*)&qs[base + (size_t)row*64 + slot*8];
    *(float4*)&Kb[row][sl*8] = qd;
  }
  __syncthreads();
  // phase 2: attn[n][e] = 0.125 * sum_d Q[n][d] kv[d][e]
  short8 bkv[2][4];
  #pragma unroll
  for (int s=0;s<2;++s){
    int sw2 = ((s*4 + kg)&3)<<4;          // (row>>3)&3 for rows s*32+kg*8+jj
    #pragma unroll
    for (int nt=0;nt<4;++nt){
      short8 bf;
      #pragma unroll
      for (int jj=0;jj<8;++jj) bf[jj] = (short)kvb[s*32 + kg*8 + jj][(nt*16 + r16) ^ sw2];
      bkv[s][nt] = bf;
    }
  }
  for (int mt=w; mt<13; mt+=4){
    f32x4 a2[4] = {};
    short8 qa[2];
    #pragma unroll
    for (int s=0;s<2;++s){
      int rr = mt*16 + r16;
      qa[s] = *(const short8*)&Kb[rr][(((s*4+kg)^(rr&7)))*8];
    }
    #pragma unroll
    for (int s=0;s<2;++s)
      #pragma unroll
      for (int nt=0;nt<4;++nt)
        a2[nt] = __builtin_amdgcn_mfma_f32_16x16x32_bf16(qa[s], bkv[s][nt], a2[nt],0,0,0);
    #pragma unroll
    for (int nt=0;nt<4;++nt){
      int e = nt*16 + r16;
      #pragma unroll
      for (int i=0;i<4;++i){
        int n = mt*16 + kg*4 + i;
        if (n < NNQ) attn[base + (size_t)n*64 + e] = a2[nt][i]*0.125f;
      }
    }
  }
}

// ---- LIF scan on attention out -> bf16 spikes [tt,(b,n),C] (x4 over e) ----
__global__ void k_lif_attn(const float* __restrict__ ain, const float* __restrict__ w,
                           float* __restrict__ vo, u16* __restrict__ sp, int t0, int tc){
  int g4 = blockIdx.x*256 + threadIdx.x;
  int e = (g4 & 15)*4;
  int n = (g4>>4) % NNQ;
  int h = (g4/(NNQ*16)) & 7;
  int b = g4/(NNQ*16*8);
  size_t e0 = (size_t)g4*4;
  size_t dst = (size_t)(b*NNQ + n)*CC + h*HD + e;
  float sg = sigm(w[0]);
  float4 v;
  if (t0==0){ v.x=0.f; v.y=0.f; v.z=0.f; v.w=0.f; }
  else v = *(const float4*)&vo[e0];
  for (int tt=0; tt<tc; ++tt){
    float4 xv = *(const float4*)&ain[(size_t)tt*PT + e0];
    ushort4 ov;
    ov.x = (lif_step(xv.x, v.x, sg)!=0.f) ? 0x3F80 : 0;
    ov.y = (lif_step(xv.y, v.y, sg)!=0.f) ? 0x3F80 : 0;
    ov.z = (lif_step(xv.z, v.z, sg)!=0.f) ? 0x3F80 : 0;
    ov.w = (lif_step(xv.w, v.w, sg)!=0.f) ? 0x3F80 : 0;
    *(ushort4*)&sp[(size_t)tt*PT + dst] = ov;
  }
  *(float4*)&vo[e0] = v;
}

// ---- BN2 apply in-place on Y (proj GEMM already wrote there) ----
__global__ void k_bn2_apply(float* __restrict__ Y, const float* __restrict__ mean,
                            const float* __restrict__ rstd, const float* __restrict__ g2,
                            const float* __restrict__ b2, int t0){
  size_t idx = ((size_t)blockIdx.x*256 + threadIdx.x)*4;
  int tt = (int)(idx / PT);
  size_t off = idx - (size_t)tt*PT;
  int c = (int)(off & (CC-1));
  float4 xv = *(const float4*)&Y[idx];
  float4 mv = *(const float4*)&mean[tt*CC + c];
  float4 rv = *(const float4*)&rstd[tt*CC + c];
  float4 gv = *(const float4*)&g2[(t0+tt)*CC + c];
  float4 bv = *(const float4*)&b2[(t0+tt)*CC + c];
  float4 yv;
  yv.x = __fadd_rn(__fmul_rn(__fmul_rn(__fsub_rn(xv.x, mv.x), rv.x), gv.x), bv.x);
  yv.y = __fadd_rn(__fmul_rn(__fmul_rn(__fsub_rn(xv.y, mv.y), rv.y), gv.y), bv.y);
  yv.z = __fadd_rn(__fmul_rn(__fmul_rn(__fsub_rn(xv.z, mv.z), rv.z), gv.z), bv.z);
  yv.w = __fadd_rn(__fmul_rn(__fmul_rn(__fsub_rn(xv.w, mv.w), rv.w), gv.w), bv.w);
  *(float4*)&Y[idx] = yv;
}

extern "C" void kernel_launch(void* const* d_in, const int* in_sizes, int n_in,
                              void* d_out, int out_size, void* d_ws, size_t ws_size,
                              hipStream_t stream){
  const float* x      = (const float*)d_in[0];
  const float* qkv_w  = (const float*)d_in[1];
  const float* qkv_b  = (const float*)d_in[2];
  const float* bn1_g  = (const float*)d_in[3];
  const float* bn1_b  = (const float*)d_in[4];
  const float* proj_w = (const float*)d_in[5];
  const float* proj_b = (const float*)d_in[6];
  const float* bn2_g  = (const float*)d_in[7];
  const float* bn2_b  = (const float*)d_in[8];
  const float* w_in   = (const float*)d_in[9];
  const float* w_q    = (const float*)d_in[10];
  const float* w_k    = (const float*)d_in[11];
  const float* w_v    = (const float*)d_in[12];
  const float* w_proj = (const float*)d_in[13];
  float* outp = (float*)d_out;

  auto need = [](int tc)->size_t{
    return 4ull*5*PT + 8ull*tc*O3 + 8ull*tc*CC
         + 16ull*tc*O3*NRG + 16ull*tc*CC*NRG
         + 6ull*WTOT
         + 10ull*tc*PT
         + 4ull*tc*BN*O3;
  };
  int TC = 16;
  while (TC > 1 && need(TC) > ws_size) TC >>= 1;

  char* p = (char*)d_ws;
  float* vin = (float*)p; p += 4ull*PT;
  float* vq  = (float*)p; p += 4ull*PT;
  float* vk  = (float*)p; p += 4ull*PT;
  float* vv  = (float*)p; p += 4ull*PT;
  float* vo  = (float*)p; p += 4ull*PT;
  float* mean1 = (float*)p; p += 4ull*TC*O3;
  float* rstd1 = (float*)p; p += 4ull*TC*O3;
  float* mean2 = (float*)p; p += 4ull*TC*CC;
  float* rstd2 = (float*)p; p += 4ull*TC*CC;
  double* p1sum = (double*)p; p += 8ull*TC*O3*NRG;
  double* p1sq  = (double*)p; p += 8ull*TC*O3*NRG;
  double* p2sum = (double*)p; p += 8ull*TC*CC*NRG;
  double* p2sq  = (double*)p; p += 8ull*TC*CC*NRG;
  u16* whi  = (u16*)p; p += 2ull*WTOT;
  u16* wmid = (u16*)p; p += 2ull*WTOT;
  u16* wlo  = (u16*)p; p += 2ull*WTOT;
  u16* s0    = (u16*)p; p += 2ull*TC*PT;
  u16* qsb   = (u16*)p; p += 2ull*TC*PT;
  u16* ksb   = (u16*)p; p += 2ull*TC*PT;
  u16* vsb   = (u16*)p; p += 2ull*TC*PT;
  u16* sproj = (u16*)p; p += 2ull*TC*PT;
  float* qkv_all = (float*)p;                 // tc*BN*O3 floats
  float* attn    = qkv_all;                   // tc*PT (overlaps dead qkv_all)

  k_wsplit<<<WTOT/256, 256, 0, stream>>>(qkv_w, proj_w, whi, wmid, wlo);

  for (int t0=0; t0<TT; t0+=TC){
    int M = TC*BN;
    int nMB = (M+127)/128;
    float* outc = outp + (size_t)t0*PT;
    k_lif_x<<<PT/1024, 256, 0, stream>>>(x, w_in, vin, s0, t0, TC);

    k_gemm_mfma<O3,3><<<nMB*(O3/128), 256, 0, stream>>>(
        s0, whi, wmid, wlo, qkv_b, qkv_all, M);

    k_stat_part<O3><<<dim3(O3/256, TC, NRG), dim3(64,4), 0, stream>>>(qkv_all, p1sum, p1sq);
    if (TC == 16)
      k_stat_reduce<O3,16><<<(16*O3+255)/256, 256, 0, stream>>>(p1sum, p1sq, mean1, rstd1);
    else if (TC == 8)
      k_stat_reduce<O3,8><<<(8*O3+255)/256, 256, 0, stream>>>(p1sum, p1sq, mean1, rstd1);
    else
      k_stat_reduce<O3,4><<<(4*O3+255)/256, 256, 0, stream>>>(p1sum, p1sq, mean1, rstd1);

    k_lif_qkv<<<dim3(PT/1024, 3), 256, 0, stream>>>(qkv_all, mean1, rstd1, bn1_g, bn1_b,
                                                    w_q, w_k, w_v, vq, vk, vv,
                                                    qsb, ksb, vsb, t0, TC);

    k_kvqv_mfma<<<TC*BB*HH, 256, 0, stream>>>(ksb, vsb, qsb, attn);

    k_lif_attn<<<PT/1024, 256, 0, stream>>>(attn, w_proj, vo, sproj, t0, TC);

    k_gemm_mfma<CC,2><<<nMB*(CC/128), 256, 0, stream>>>(
        sproj, whi + (size_t)O3*CC, wmid + (size_t)O3*CC, wlo + (size_t)O3*CC,
        proj_b, outc, M);

    k_stat_part<CC><<<dim3(CC/256, TC, NRG), dim3(64,4), 0, stream>>>(outc, p2sum, p2sq);
    if (TC == 16)
      k_stat_reduce<CC,16><<<(16*CC+255)/256, 256, 0, stream>>>(p2sum, p2sq, mean2, rstd2);
    else if (TC == 8)
      k_stat_reduce<CC,8><<<(8*CC+255)/256, 256, 0, stream>>>(p2sum, p2sq, mean2, rstd2);
    else
      k_stat_reduce<CC,4><<<(4*CC+255)/256, 256, 0, stream>>>(p2sum, p2sq, mean2, rstd2);

    k_bn2_apply<<<(TC*(size_t)PT)/1024, 256, 0, stream>>>(outc, mean2, rstd2,
                                                          bn2_g, bn2_b, t0);
  }
}